// Round 2
// baseline (296.869 us; speedup 1.0000x reference)
//
#include <hip/hip_runtime.h>
#include <math.h>

// NetVLAD fused forward, fp32, MI355X.
// B=64, L=4096, D=128, K=64.
#define NB 64
#define NL 4096
#define ND 128
#define NK 64
#define NS 8            // slices per batch item (grid = NB*NS = 512 blocks)
#define LC (NL / NS)    // 512 rows per block
#define LT 64           // rows per tile
#define NT (LC / LT)    // 8 tiles per block

// ---------------------------------------------------------------------------
// Kernel A: per (b, slice): L2-normalize rows, logits GEMM + softmax,
// pooling GEMM into register accumulators; write partial vlad + partial asum.
// LDS = 32K(xs) + 32K(Wt) + 16K(a) = 80 KiB exactly -> 2 blocks/CU.
// ---------------------------------------------------------------------------
__global__ __launch_bounds__(256, 2)
void vlad_partial_kernel(const float* __restrict__ x,
                         const float* __restrict__ Wg,   // assign_w [K][D]
                         const float* __restrict__ bg,   // assign_b [K]
                         float* __restrict__ wsv,        // [B][S][K][D] partials
                         float* __restrict__ wsa)        // [B][S][K] partial asum
{
    __shared__ __attribute__((aligned(16))) float xs[LT * ND];  // swizzled x tile
    __shared__ __attribute__((aligned(16))) float Wt[ND * NK];  // Wt[d][k]
    __shared__ __attribute__((aligned(16))) float aS[LT * NK];  // a[row][k]

    const int tid = threadIdx.x;
    const int b = blockIdx.x / NS;
    const int s = blockIdx.x % NS;

    // ---- stage Wt = transpose(assign_w), conflict-free writes ----
    {
        const int k0 = tid & 63;       // lane-contiguous k for LDS writes
        const int db = tid >> 6;       // 32-wide d block per wave
        const float4* wr = reinterpret_cast<const float4*>(Wg + k0 * ND + db * 32);
#pragma unroll
        for (int i = 0; i < 8; ++i) {
            float4 wv = wr[i];
            const int dbase = db * 32 + i * 4;
            Wt[(dbase + 0) * NK + k0] = wv.x;
            Wt[(dbase + 1) * NK + k0] = wv.y;
            Wt[(dbase + 2) * NK + k0] = wv.z;
            Wt[(dbase + 3) * NK + k0] = wv.w;
        }
    }

    // logits mapping: thread (tr, tc) owns rows 4*tr..+3, ks 4*tc..+3
    const int tc = tid & 15;
    const int tr = tid >> 4;
    // pooling mapping: thread (tk, td) owns ks 4*tk..+3, ds 8*td..+7
    const int td = tid & 15;
    const int tk = tid >> 4;
    // load mapping: 4 threads per row
    const int lrow = tid >> 2;
    const int lpart = tid & 3;

    float bias[4];
#pragma unroll
    for (int j = 0; j < 4; ++j) bias[j] = bg[4 * tc + j];

    float acc[4][8];
#pragma unroll
    for (int i = 0; i < 4; ++i)
#pragma unroll
        for (int j = 0; j < 8; ++j) acc[i][j] = 0.f;
    float asum[4] = {0.f, 0.f, 0.f, 0.f};

    const int swzW = ((lrow >> 2) & 3) << 2;   // write-side swizzle (by row)
    const int swzL = (tr & 3) << 2;            // logits read-side swizzle (row>>2 == tr)

    const float* xb = x + ((size_t)b * NL + (size_t)s * LC) * ND;

    for (int t = 0; t < NT; ++t) {
        __syncthreads();   // previous tile's pooling done before overwriting xs/aS

        // ---- load + row L2-normalize into xs (swizzled on d bits 2..3) ----
        {
            const float4* xr = reinterpret_cast<const float4*>(
                xb + (size_t)(t * LT + lrow) * ND + lpart * 32);
            float4 v[8];
            float ss = 0.f;
#pragma unroll
            for (int i = 0; i < 8; ++i) {
                v[i] = xr[i];
                ss += v[i].x * v[i].x + v[i].y * v[i].y + v[i].z * v[i].z + v[i].w * v[i].w;
            }
            ss += __shfl_xor(ss, 1);
            ss += __shfl_xor(ss, 2);
            const float sc = 1.f / fmaxf(sqrtf(ss), 1e-12f);
            float* xrow = &xs[lrow * ND];
#pragma unroll
            for (int i = 0; i < 8; ++i) {
                const int d0 = (lpart * 32 + i * 4) ^ swzW;
                float4 w;
                w.x = v[i].x * sc; w.y = v[i].y * sc;
                w.z = v[i].z * sc; w.w = v[i].w * sc;
                *reinterpret_cast<float4*>(&xrow[d0]) = w;
            }
        }
        __syncthreads();

        // ---- logits: C[4r][4k] = xs(rows) * Wt + bias ----
        float C0[4][4];
#pragma unroll
        for (int r = 0; r < 4; ++r)
#pragma unroll
            for (int j = 0; j < 4; ++j) C0[r][j] = bias[j];

#pragma unroll 2
        for (int d = 0; d < ND; d += 4) {
            const float4 w0 = *reinterpret_cast<const float4*>(&Wt[(d + 0) * NK + 4 * tc]);
            const float4 w1 = *reinterpret_cast<const float4*>(&Wt[(d + 1) * NK + 4 * tc]);
            const float4 w2 = *reinterpret_cast<const float4*>(&Wt[(d + 2) * NK + 4 * tc]);
            const float4 w3 = *reinterpret_cast<const float4*>(&Wt[(d + 3) * NK + 4 * tc]);
#pragma unroll
            for (int r = 0; r < 4; ++r) {
                const int row = 4 * tr + r;
                const float4 xv = *reinterpret_cast<const float4*>(&xs[row * ND + (d ^ swzL)]);
                C0[r][0] = fmaf(xv.x, w0.x, C0[r][0]);
                C0[r][1] = fmaf(xv.x, w0.y, C0[r][1]);
                C0[r][2] = fmaf(xv.x, w0.z, C0[r][2]);
                C0[r][3] = fmaf(xv.x, w0.w, C0[r][3]);
                C0[r][0] = fmaf(xv.y, w1.x, C0[r][0]);
                C0[r][1] = fmaf(xv.y, w1.y, C0[r][1]);
                C0[r][2] = fmaf(xv.y, w1.z, C0[r][2]);
                C0[r][3] = fmaf(xv.y, w1.w, C0[r][3]);
                C0[r][0] = fmaf(xv.z, w2.x, C0[r][0]);
                C0[r][1] = fmaf(xv.z, w2.y, C0[r][1]);
                C0[r][2] = fmaf(xv.z, w2.z, C0[r][2]);
                C0[r][3] = fmaf(xv.z, w2.w, C0[r][3]);
                C0[r][0] = fmaf(xv.w, w3.x, C0[r][0]);
                C0[r][1] = fmaf(xv.w, w3.y, C0[r][1]);
                C0[r][2] = fmaf(xv.w, w3.z, C0[r][2]);
                C0[r][3] = fmaf(xv.w, w3.w, C0[r][3]);
            }
        }

        // ---- softmax over k (4 regs x 16 tc-lanes) -> aS, accumulate asum ----
#pragma unroll
        for (int r = 0; r < 4; ++r) {
            float m = fmaxf(fmaxf(C0[r][0], C0[r][1]), fmaxf(C0[r][2], C0[r][3]));
            m = fmaxf(m, __shfl_xor(m, 1));
            m = fmaxf(m, __shfl_xor(m, 2));
            m = fmaxf(m, __shfl_xor(m, 4));
            m = fmaxf(m, __shfl_xor(m, 8));
            const float e0 = __expf(C0[r][0] - m);
            const float e1 = __expf(C0[r][1] - m);
            const float e2 = __expf(C0[r][2] - m);
            const float e3 = __expf(C0[r][3] - m);
            float sm = e0 + e1 + e2 + e3;
            sm += __shfl_xor(sm, 1);
            sm += __shfl_xor(sm, 2);
            sm += __shfl_xor(sm, 4);
            sm += __shfl_xor(sm, 8);
            const float inv = 1.f / sm;
            float4 av;
            av.x = e0 * inv; av.y = e1 * inv; av.z = e2 * inv; av.w = e3 * inv;
            asum[0] += av.x; asum[1] += av.y; asum[2] += av.z; asum[3] += av.w;
            *reinterpret_cast<float4*>(&aS[(4 * tr + r) * NK + 4 * tc]) = av;
        }
        __syncthreads();

        // ---- pooling: acc[k][d] += a[l][k] * xs[l][d] ----
#pragma unroll 2
        for (int l = 0; l < LT; ++l) {
            const float4 af = *reinterpret_cast<const float4*>(&aS[l * NK + 4 * tk]);
            const int dd = (8 * td) ^ (((l >> 2) & 3) << 2);
            const float* xrow = &xs[l * ND];
            const float4 x0 = *reinterpret_cast<const float4*>(&xrow[dd]);
            const float4 x1 = *reinterpret_cast<const float4*>(&xrow[dd ^ 4]);
            acc[0][0] = fmaf(af.x, x0.x, acc[0][0]);
            acc[0][1] = fmaf(af.x, x0.y, acc[0][1]);
            acc[0][2] = fmaf(af.x, x0.z, acc[0][2]);
            acc[0][3] = fmaf(af.x, x0.w, acc[0][3]);
            acc[0][4] = fmaf(af.x, x1.x, acc[0][4]);
            acc[0][5] = fmaf(af.x, x1.y, acc[0][5]);
            acc[0][6] = fmaf(af.x, x1.z, acc[0][6]);
            acc[0][7] = fmaf(af.x, x1.w, acc[0][7]);
            acc[1][0] = fmaf(af.y, x0.x, acc[1][0]);
            acc[1][1] = fmaf(af.y, x0.y, acc[1][1]);
            acc[1][2] = fmaf(af.y, x0.z, acc[1][2]);
            acc[1][3] = fmaf(af.y, x0.w, acc[1][3]);
            acc[1][4] = fmaf(af.y, x1.x, acc[1][4]);
            acc[1][5] = fmaf(af.y, x1.y, acc[1][5]);
            acc[1][6] = fmaf(af.y, x1.z, acc[1][6]);
            acc[1][7] = fmaf(af.y, x1.w, acc[1][7]);
            acc[2][0] = fmaf(af.z, x0.x, acc[2][0]);
            acc[2][1] = fmaf(af.z, x0.y, acc[2][1]);
            acc[2][2] = fmaf(af.z, x0.z, acc[2][2]);
            acc[2][3] = fmaf(af.z, x0.w, acc[2][3]);
            acc[2][4] = fmaf(af.z, x1.x, acc[2][4]);
            acc[2][5] = fmaf(af.z, x1.y, acc[2][5]);
            acc[2][6] = fmaf(af.z, x1.z, acc[2][6]);
            acc[2][7] = fmaf(af.z, x1.w, acc[2][7]);
            acc[3][0] = fmaf(af.w, x0.x, acc[3][0]);
            acc[3][1] = fmaf(af.w, x0.y, acc[3][1]);
            acc[3][2] = fmaf(af.w, x0.z, acc[3][2]);
            acc[3][3] = fmaf(af.w, x0.w, acc[3][3]);
            acc[3][4] = fmaf(af.w, x1.x, acc[3][4]);
            acc[3][5] = fmaf(af.w, x1.y, acc[3][5]);
            acc[3][6] = fmaf(af.w, x1.z, acc[3][6]);
            acc[3][7] = fmaf(af.w, x1.w, acc[3][7]);
        }
    }

    // ---- write partial vlad ----
    float* ob = wsv + (size_t)(b * NS + s) * NK * ND;
#pragma unroll
    for (int i = 0; i < 4; ++i) {
        const int k = 4 * tk + i;
        float4 lo, hi;
        lo.x = acc[i][0]; lo.y = acc[i][1]; lo.z = acc[i][2]; lo.w = acc[i][3];
        hi.x = acc[i][4]; hi.y = acc[i][5]; hi.z = acc[i][6]; hi.w = acc[i][7];
        *reinterpret_cast<float4*>(&ob[k * ND + 8 * td]) = lo;
        *reinterpret_cast<float4*>(&ob[k * ND + 8 * td + 4]) = hi;
    }

    // ---- reduce asum over the 16 tr-groups, write partial asum ----
#pragma unroll
    for (int j = 0; j < 4; ++j) {
        float v = asum[j];
        v += __shfl_xor(v, 16);
        v += __shfl_xor(v, 32);
        asum[j] = v;
    }
    __syncthreads();                 // aS reusable as scratch now
    const int wave = tid >> 6;
    if ((tid & 63) < 16) {           // one tr-representative per wave, tc = tid&15
#pragma unroll
        for (int j = 0; j < 4; ++j) aS[wave * NK + 4 * (tid & 15) + j] = asum[j];
    }
    __syncthreads();
    if (tid < NK) {
        const float v = aS[0 * NK + tid] + aS[1 * NK + tid] +
                        aS[2 * NK + tid] + aS[3 * NK + tid];
        wsa[(size_t)(b * NS + s) * NK + tid] = v;
    }
}

// ---------------------------------------------------------------------------
// Kernel B: reduce NS partials, subtract asum*centroid, intra-cluster L2
// normalize, BatchNorm (inference), write output. One wave per (b,k).
// ---------------------------------------------------------------------------
__global__ __launch_bounds__(64)
void vlad_finalize_kernel(const float* __restrict__ wsv,
                          const float* __restrict__ wsa,
                          const float* __restrict__ cen,
                          const float* __restrict__ gam,
                          const float* __restrict__ bet,
                          const float* __restrict__ mu,
                          const float* __restrict__ var,
                          float* __restrict__ out)
{
    const int bk = blockIdx.x;
    const int b = bk >> 6;
    const int k = bk & 63;
    const int lane = threadIdx.x;

    const float* vb = wsv + (size_t)b * NS * NK * ND + (size_t)k * ND;
    float v0 = 0.f, v1 = 0.f, as = 0.f;
#pragma unroll
    for (int s = 0; s < NS; ++s) {
        const float* p = vb + (size_t)s * NK * ND;
        v0 += p[lane];
        v1 += p[lane + 64];
        as += wsa[(b * NS + s) * NK + k];
    }
    const int i0 = k * ND + lane;
    const int i1 = i0 + 64;
    v0 -= as * cen[i0];
    v1 -= as * cen[i1];

    float ss = v0 * v0 + v1 * v1;
#pragma unroll
    for (int o = 1; o < 64; o <<= 1) ss += __shfl_xor(ss, o);
    const float sc = 1.f / fmaxf(sqrtf(ss), 1e-12f);

    const float n0 = v0 * sc;
    const float n1 = v1 * sc;
    float* ob = out + (size_t)b * NK * ND;
    ob[i0] = gam[i0] * (n0 - mu[i0]) * rsqrtf(var[i0] + 1e-5f) + bet[i0];
    ob[i1] = gam[i1] * (n1 - mu[i1]) * rsqrtf(var[i1] + 1e-5f) + bet[i1];
}

extern "C" void kernel_launch(void* const* d_in, const int* in_sizes, int n_in,
                              void* d_out, int out_size, void* d_ws, size_t ws_size,
                              hipStream_t stream) {
    const float* x  = (const float*)d_in[0];
    const float* aw = (const float*)d_in[1];
    const float* ab = (const float*)d_in[2];
    const float* ce = (const float*)d_in[3];
    const float* g  = (const float*)d_in[4];
    const float* be = (const float*)d_in[5];
    const float* mu = (const float*)d_in[6];
    const float* va = (const float*)d_in[7];
    float* out = (float*)d_out;

    float* wsv = (float*)d_ws;                              // B*S*K*D floats (16 MiB)
    float* wsa = wsv + (size_t)NB * NS * NK * ND;           // B*S*K floats (128 KiB)

    hipLaunchKernelGGL(vlad_partial_kernel, dim3(NB * NS), dim3(256), 0, stream,
                       x, aw, ab, wsv, wsa);
    hipLaunchKernelGGL(vlad_finalize_kernel, dim3(NB * NK), dim3(64), 0, stream,
                       wsv, wsa, ce, g, be, mu, va, out);
}

// Round 4
// 286.610 us; speedup vs baseline: 1.0358x; 1.0358x over previous
//
#include <hip/hip_runtime.h>
#include <math.h>

// NetVLAD fused forward, fp32, MI355X.
// B=64, L=4096, D=128, K=64.
#define NB 64
#define NL 4096
#define ND 128
#define NK 64
#define NS 8            // slices per batch item (grid = NB*NS = 512 blocks)
#define LC (NL / NS)    // 512 rows per block
#define LT 64           // rows per tile
#define NT (LC / LT)    // 8 tiles per block

// LDS swizzle (xs only): phys float-col = col ^ ((row&7)<<2).
// Write: 8 lanes/bank-quad balanced. Logits read: 16(g^(tr&1)) + 4(m^r),
// 2-way (free). Pooling read: ((td^(lp&7))<<4), 2-way (free).

__global__ __launch_bounds__(256, 2)
void vlad_partial_kernel(const float* __restrict__ x,
                         const float* __restrict__ Wg,   // assign_w [K][D]
                         const float* __restrict__ bg,   // assign_b [K]
                         float* __restrict__ wsv,        // [B][S][K][D] partials
                         float* __restrict__ wsa)        // [B][S][K] partial asum
{
    __shared__ __attribute__((aligned(16))) float xs[LT * ND];  // swizzled x tile
    __shared__ __attribute__((aligned(16))) float Wt[ND * NK];  // Wt[d][k]
    __shared__ __attribute__((aligned(16))) float aS[LT * NK];  // a[row][k]

    const int tid = threadIdx.x;
    const int b = blockIdx.x / NS;
    const int s = blockIdx.x % NS;

    // staging mapping: 4 lanes per row, lane owns cols {(tid&3)*4 + 16i}
    const int srow = tid >> 2;           // 0..63
    const int scol = (tid & 3) << 2;     // 0,4,8,12
    const int swz = (srow & 7) << 2;     // 3-bit row swizzle
    const float* xb = x + ((size_t)b * NL + (size_t)s * LC) * ND;

    // ---- prefetch tile 0 into registers ----
    float4 v[8];
    {
        const float* g0 = xb + (size_t)srow * ND + scol;
#pragma unroll
        for (int i = 0; i < 8; ++i)
            v[i] = *reinterpret_cast<const float4*>(g0 + 16 * i);
    }

    // ---- stage Wt = transpose(assign_w) (b32 writes, 2-way max) ----
    {
        const int k0 = tid & 63;
        const int db = tid >> 6;
        const float4* wr = reinterpret_cast<const float4*>(Wg + k0 * ND + db * 32);
#pragma unroll
        for (int i = 0; i < 8; ++i) {
            float4 wv = wr[i];
            const int dbase = db * 32 + i * 4;
            Wt[(dbase + 0) * NK + k0] = wv.x;
            Wt[(dbase + 1) * NK + k0] = wv.y;
            Wt[(dbase + 2) * NK + k0] = wv.z;
            Wt[(dbase + 3) * NK + k0] = wv.w;
        }
    }

    // logits mapping: thread (tr, tc) owns rows 4*tr..+3, ks 4*tc..+3
    const int tc = tid & 15;
    const int tr = tid >> 4;
    const int gflip = tr & 1;            // logits g-group flip from row swizzle
    // pooling mapping: thread (tk, td) owns ks 4*tk..+3, cols {4td..}+{64+4td..}
    const int td = tid & 15;
    const int tk = tid >> 4;

    float bias[4];
#pragma unroll
    for (int j = 0; j < 4; ++j) bias[j] = bg[4 * tc + j];

    float acc[4][8];
#pragma unroll
    for (int i = 0; i < 4; ++i)
#pragma unroll
        for (int j = 0; j < 8; ++j) acc[i][j] = 0.f;
    float asum[4] = {0.f, 0.f, 0.f, 0.f};

    // pooling swizzled byte offsets, indexed by (lp&7) statically
    int bq[8];
#pragma unroll
    for (int j = 0; j < 8; ++j) bq[j] = (td ^ j) << 4;

    // logits per-r row byte pointers
    const char* px0 = (const char*)xs + (size_t)(4 * tr + 0) * (ND * 4);
    const char* px1 = (const char*)xs + (size_t)(4 * tr + 1) * (ND * 4);
    const char* px2 = (const char*)xs + (size_t)(4 * tr + 2) * (ND * 4);
    const char* px3 = (const char*)xs + (size_t)(4 * tr + 3) * (ND * 4);

    for (int t = 0; t < NT; ++t) {
        // ---- row L2 norm from registers ----
        float ss = 0.f;
#pragma unroll
        for (int i = 0; i < 8; ++i)
            ss += v[i].x * v[i].x + v[i].y * v[i].y + v[i].z * v[i].z + v[i].w * v[i].w;
        ss += __shfl_xor(ss, 1);
        ss += __shfl_xor(ss, 2);
        const float sc = 1.f / fmaxf(sqrtf(ss), 1e-12f);

        __syncthreads();   // previous tile's pooling done reading xs/aS

        // ---- write normalized tile, swizzled ----
        {
            float* xrow = xs + srow * ND;
#pragma unroll
            for (int i = 0; i < 8; ++i) {
                float4 w;
                w.x = v[i].x * sc; w.y = v[i].y * sc;
                w.z = v[i].z * sc; w.w = v[i].w * sc;
                *reinterpret_cast<float4*>(xrow + ((scol + 16 * i) ^ swz)) = w;
            }
        }

        // ---- issue prefetch for tile t+1 (latency hides under compute) ----
        if (t + 1 < NT) {
            const float* g1 = xb + (size_t)((t + 1) * LT + srow) * ND + scol;
#pragma unroll
            for (int i = 0; i < 8; ++i)
                v[i] = *reinterpret_cast<const float4*>(g1 + 16 * i);
        }

        __syncthreads();   // xs ready

        // ---- logits: C[4r][4k] = xs(rows) * Wt + bias ----
        float C0[4][4];
#pragma unroll
        for (int r = 0; r < 4; ++r)
#pragma unroll
            for (int j = 0; j < 4; ++j) C0[r][j] = bias[j];

        {
            const char* wt_p = (const char*)Wt + tc * 16;
#pragma unroll 2
            for (int g = 0; g < 8; ++g) {
                const int go = (g ^ gflip) << 6;   // phys group byte offset
#pragma unroll
                for (int m = 0; m < 4; ++m) {
                    // logical d = 16g + 4m
                    const float4 w0 = *reinterpret_cast<const float4*>(wt_p + (size_t)g * 4096 + (4 * m + 0) * 256);
                    const float4 w1 = *reinterpret_cast<const float4*>(wt_p + (size_t)g * 4096 + (4 * m + 1) * 256);
                    const float4 w2 = *reinterpret_cast<const float4*>(wt_p + (size_t)g * 4096 + (4 * m + 2) * 256);
                    const float4 w3 = *reinterpret_cast<const float4*>(wt_p + (size_t)g * 4096 + (4 * m + 3) * 256);
                    // per r: phys slot (m^r), phys group (g^gflip)
                    const float4 xv0 = *reinterpret_cast<const float4*>(px0 + go + ((m ^ 0) << 4));
                    const float4 xv1 = *reinterpret_cast<const float4*>(px1 + go + ((m ^ 1) << 4));
                    const float4 xv2 = *reinterpret_cast<const float4*>(px2 + go + ((m ^ 2) << 4));
                    const float4 xv3 = *reinterpret_cast<const float4*>(px3 + go + ((m ^ 3) << 4));
#define LOGITS_FMA(rr, xv)                                            \
                    C0[rr][0] = fmaf(xv.x, w0.x, C0[rr][0]);          \
                    C0[rr][1] = fmaf(xv.x, w0.y, C0[rr][1]);          \
                    C0[rr][2] = fmaf(xv.x, w0.z, C0[rr][2]);          \
                    C0[rr][3] = fmaf(xv.x, w0.w, C0[rr][3]);          \
                    C0[rr][0] = fmaf(xv.y, w1.x, C0[rr][0]);          \
                    C0[rr][1] = fmaf(xv.y, w1.y, C0[rr][1]);          \
                    C0[rr][2] = fmaf(xv.y, w1.z, C0[rr][2]);          \
                    C0[rr][3] = fmaf(xv.y, w1.w, C0[rr][3]);          \
                    C0[rr][0] = fmaf(xv.z, w2.x, C0[rr][0]);          \
                    C0[rr][1] = fmaf(xv.z, w2.y, C0[rr][1]);          \
                    C0[rr][2] = fmaf(xv.z, w2.z, C0[rr][2]);          \
                    C0[rr][3] = fmaf(xv.z, w2.w, C0[rr][3]);          \
                    C0[rr][0] = fmaf(xv.w, w3.x, C0[rr][0]);          \
                    C0[rr][1] = fmaf(xv.w, w3.y, C0[rr][1]);          \
                    C0[rr][2] = fmaf(xv.w, w3.z, C0[rr][2]);          \
                    C0[rr][3] = fmaf(xv.w, w3.w, C0[rr][3]);
                    LOGITS_FMA(0, xv0)
                    LOGITS_FMA(1, xv1)
                    LOGITS_FMA(2, xv2)
                    LOGITS_FMA(3, xv3)
#undef LOGITS_FMA
                }
            }
        }

        // ---- softmax over k -> aS, accumulate asum ----
#pragma unroll
        for (int r = 0; r < 4; ++r) {
            float m = fmaxf(fmaxf(C0[r][0], C0[r][1]), fmaxf(C0[r][2], C0[r][3]));
            m = fmaxf(m, __shfl_xor(m, 1));
            m = fmaxf(m, __shfl_xor(m, 2));
            m = fmaxf(m, __shfl_xor(m, 4));
            m = fmaxf(m, __shfl_xor(m, 8));
            const float e0 = __expf(C0[r][0] - m);
            const float e1 = __expf(C0[r][1] - m);
            const float e2 = __expf(C0[r][2] - m);
            const float e3 = __expf(C0[r][3] - m);
            float sm = e0 + e1 + e2 + e3;
            sm += __shfl_xor(sm, 1);
            sm += __shfl_xor(sm, 2);
            sm += __shfl_xor(sm, 4);
            sm += __shfl_xor(sm, 8);
            const float inv = 1.f / sm;
            float4 av;
            av.x = e0 * inv; av.y = e1 * inv; av.z = e2 * inv; av.w = e3 * inv;
            asum[0] += av.x; asum[1] += av.y; asum[2] += av.z; asum[3] += av.w;
            *reinterpret_cast<float4*>(&aS[(4 * tr + r) * NK + 4 * tc]) = av;
        }
        __syncthreads();   // aS ready

        // ---- pooling: acc[k][cols] += a[l][k] * xs[l][cols] ----
        {
            const char* pxr = (const char*)xs;
            const char* par = (const char*)aS + (tk << 4);
            for (int lp0 = 0; lp0 < LT; lp0 += 8) {
#pragma unroll
                for (int jj = 0; jj < 8; ++jj) {
                    const int lp = lp0 + jj;           // lp&7 == jj (static)
                    const float4 af = *reinterpret_cast<const float4*>(par + lp * 256);
                    const float4 x0 = *reinterpret_cast<const float4*>(pxr + lp * 512 + bq[jj]);
                    const float4 x1 = *reinterpret_cast<const float4*>(pxr + lp * 512 + bq[jj] + 256);
#define POOL_FMA(ii, aa)                                   \
                    acc[ii][0] = fmaf(aa, x0.x, acc[ii][0]);   \
                    acc[ii][1] = fmaf(aa, x0.y, acc[ii][1]);   \
                    acc[ii][2] = fmaf(aa, x0.z, acc[ii][2]);   \
                    acc[ii][3] = fmaf(aa, x0.w, acc[ii][3]);   \
                    acc[ii][4] = fmaf(aa, x1.x, acc[ii][4]);   \
                    acc[ii][5] = fmaf(aa, x1.y, acc[ii][5]);   \
                    acc[ii][6] = fmaf(aa, x1.z, acc[ii][6]);   \
                    acc[ii][7] = fmaf(aa, x1.w, acc[ii][7]);
                    POOL_FMA(0, af.x)
                    POOL_FMA(1, af.y)
                    POOL_FMA(2, af.z)
                    POOL_FMA(3, af.w)
#undef POOL_FMA
                }
            }
        }
    }

    // ---- write partial vlad: cols [4td..4td+3] and [64+4td..] ----
    float* ob = wsv + (size_t)(b * NS + s) * NK * ND;
#pragma unroll
    for (int i = 0; i < 4; ++i) {
        const int k = 4 * tk + i;
        float4 lo, hi;
        lo.x = acc[i][0]; lo.y = acc[i][1]; lo.z = acc[i][2]; lo.w = acc[i][3];
        hi.x = acc[i][4]; hi.y = acc[i][5]; hi.z = acc[i][6]; hi.w = acc[i][7];
        *reinterpret_cast<float4*>(&ob[k * ND + 4 * td]) = lo;
        *reinterpret_cast<float4*>(&ob[k * ND + 64 + 4 * td]) = hi;
    }

    // ---- reduce asum over the 16 tr-groups, write partial asum ----
#pragma unroll
    for (int j = 0; j < 4; ++j) {
        float vv = asum[j];
        vv += __shfl_xor(vv, 16);
        vv += __shfl_xor(vv, 32);
        asum[j] = vv;
    }
    __syncthreads();                 // aS reusable as scratch now
    const int wave = tid >> 6;
    if ((tid & 63) < 16) {
#pragma unroll
        for (int j = 0; j < 4; ++j) aS[wave * NK + 4 * (tid & 15) + j] = asum[j];
    }
    __syncthreads();
    if (tid < NK) {
        const float vv = aS[0 * NK + tid] + aS[1 * NK + tid] +
                         aS[2 * NK + tid] + aS[3 * NK + tid];
        wsa[(size_t)(b * NS + s) * NK + tid] = vv;
    }
}

// ---------------------------------------------------------------------------
// Kernel B: reduce NS partials, subtract asum*centroid, intra-cluster L2
// normalize, BatchNorm (inference), write output. One wave per (b,k).
// ---------------------------------------------------------------------------
__global__ __launch_bounds__(64)
void vlad_finalize_kernel(const float* __restrict__ wsv,
                          const float* __restrict__ wsa,
                          const float* __restrict__ cen,
                          const float* __restrict__ gam,
                          const float* __restrict__ bet,
                          const float* __restrict__ mu,
                          const float* __restrict__ var,
                          float* __restrict__ out)
{
    const int bk = blockIdx.x;
    const int b = bk >> 6;
    const int k = bk & 63;
    const int lane = threadIdx.x;

    const float* vb = wsv + (size_t)b * NS * NK * ND + (size_t)k * ND;
    float v0 = 0.f, v1 = 0.f, as = 0.f;
#pragma unroll
    for (int s = 0; s < NS; ++s) {
        const float* p = vb + (size_t)s * NK * ND;
        v0 += p[lane];
        v1 += p[lane + 64];
        as += wsa[(b * NS + s) * NK + k];
    }
    const int i0 = k * ND + lane;
    const int i1 = i0 + 64;
    v0 -= as * cen[i0];
    v1 -= as * cen[i1];

    float ss = v0 * v0 + v1 * v1;
#pragma unroll
    for (int o = 1; o < 64; o <<= 1) ss += __shfl_xor(ss, o);
    const float sc = 1.f / fmaxf(sqrtf(ss), 1e-12f);

    const float n0 = v0 * sc;
    const float n1 = v1 * sc;
    float* ob = out + (size_t)b * NK * ND;
    ob[i0] = gam[i0] * (n0 - mu[i0]) * rsqrtf(var[i0] + 1e-5f) + bet[i0];
    ob[i1] = gam[i1] * (n1 - mu[i1]) * rsqrtf(var[i1] + 1e-5f) + bet[i1];
}

extern "C" void kernel_launch(void* const* d_in, const int* in_sizes, int n_in,
                              void* d_out, int out_size, void* d_ws, size_t ws_size,
                              hipStream_t stream) {
    const float* x  = (const float*)d_in[0];
    const float* aw = (const float*)d_in[1];
    const float* ab = (const float*)d_in[2];
    const float* ce = (const float*)d_in[3];
    const float* g  = (const float*)d_in[4];
    const float* be = (const float*)d_in[5];
    const float* mu = (const float*)d_in[6];
    const float* va = (const float*)d_in[7];
    float* out = (float*)d_out;

    float* wsv = (float*)d_ws;                              // B*S*K*D floats (16 MiB)
    float* wsa = wsv + (size_t)NB * NS * NK * ND;           // B*S*K floats (128 KiB)

    hipLaunchKernelGGL(vlad_partial_kernel, dim3(NB * NS), dim3(256), 0, stream,
                       x, aw, ab, wsv, wsa);
    hipLaunchKernelGGL(vlad_finalize_kernel, dim3(NB * NK), dim3(64), 0, stream,
                       wsv, wsa, ce, g, be, mu, va, out);
}

// Round 7
// 217.504 us; speedup vs baseline: 1.3649x; 1.3177x over previous
//
#include <hip/hip_runtime.h>
#include <math.h>

// NetVLAD fused forward, MI355X. fp16-compensated MFMA version.
// B=64, L=4096, D=128, K=64.
#define NB 64
#define NL 4096
#define ND 128
#define NK 64
#define NS 8            // slices per batch item (grid = NB*NS = 512 blocks)
#define LC (NL / NS)    // 512 rows per block
#define LT 64           // rows per tile
#define NT (LC / LT)    // 8 tiles per block

typedef _Float16 h8 __attribute__((ext_vector_type(8)));
typedef _Float16 h4 __attribute__((ext_vector_type(4)));
typedef float f4 __attribute__((ext_vector_type(4)));

#define MFMA16(A, B, C) __builtin_amdgcn_mfma_f32_16x16x32_f16(A, B, C, 0, 0, 0)
#define QSCALE 2048.0f
#define QINV   4.8828125e-4f   // 2^-11

// ---- swizzled LDS index helpers (f16 units; all frag bases 16B-aligned) ----
// W[k][d] 64x128: slot(d>>3, 16/row) XOR k&15 -> frag reads conflict-free
__device__ __forceinline__ int w_idx(int k, int d) {
    return k * 128 + ((((d >> 3) ^ (k & 15)) & 15) << 3) + (d & 7);
}
// xT[d][c] 128x64: slot(c>>3, 8/row) XOR (d&7)^((d>>3)&7)
__device__ __forceinline__ int xt_idx(int d, int c) {
    return d * 64 + ((((c >> 3) ^ (d & 7) ^ ((d >> 3) & 7)) & 7) << 3) + (c & 7);
}
// aT[k][c] 64x64: slot(c>>3) XOR k&7
__device__ __forceinline__ int at_idx(int k, int c) {
    return k * 64 + ((((c >> 3) ^ (k & 7)) & 7) << 3) + (c & 7);
}

// ---------------------------------------------------------------------------
// Kernel A. Per tile: x rows staged in regs (lane = its MFMA A-frag rows),
// L2-normalize, fp16 hi/lo split; logits via 3-term MFMA (A from regs, W from
// LDS); softmax in regs; pooling via 3-term MFMA (aT,xT from LDS).
// LDS = W(32K) + xT(32K) + aT(16K) = 80 KiB -> 2 blocks/CU.
// ---------------------------------------------------------------------------
__global__ __launch_bounds__(256, 2)
void vlad_partial_kernel(const float* __restrict__ x,
                         const float* __restrict__ Wg,   // assign_w [K][D]
                         const float* __restrict__ bg,   // assign_b [K]
                         float* __restrict__ wsv,        // [B][S][K][D] partials
                         float* __restrict__ wsa)        // [B][S][K] partial asum
{
    __shared__ __attribute__((aligned(16))) _Float16 sm[40960];  // 80 KiB
    _Float16* Wh  = sm;            // 8192 = 64x128
    _Float16* Wl  = sm + 8192;
    _Float16* xTh = sm + 16384;    // 8192 = 128x64
    _Float16* xTl = sm + 24576;
    _Float16* aTh = sm + 32768;    // 4096 = 64x64
    _Float16* aTl = sm + 36864;

    const int tid = threadIdx.x;
    const int b = blockIdx.x / NS;
    const int s = blockIdx.x % NS;
    const int l   = tid & 63;     // lane
    const int w   = tid >> 6;     // wave 0..3
    const int l15 = l & 15;
    const int wl4 = l >> 4;       // 0..3 (k-subchunk / row-subgroup)

    const float* xb = x + ((size_t)b * NL + (size_t)s * LC) * ND;

    // ---- stage W as f16 hi + scaled lo (packed h4 writes, slot-uniform) ----
    {
        const int k  = tid & 63;
        const int d0 = (tid >> 6) * 32;
        const float4* wr = (const float4*)(Wg + k * ND + d0);
#pragma unroll
        for (int i = 0; i < 8; ++i) {
            float4 wv = wr[i];
            float vv[4] = {wv.x, wv.y, wv.z, wv.w};
            h4 whi, wlo;
#pragma unroll
            for (int j = 0; j < 4; ++j) {
                const _Float16 h = (_Float16)vv[j];
                whi[j] = h;
                wlo[j] = (_Float16)((vv[j] - (float)h) * QSCALE);
            }
            const int id = w_idx(k, d0 + 4 * i);   // (d&7) in {0,4}: 8B aligned
            *(h4*)(Wh + id) = whi;
            *(h4*)(Wl + id) = wlo;
        }
    }

    float bias[4];
#pragma unroll
    for (int kt = 0; kt < 4; ++kt) bias[kt] = bg[16 * kt + l15];

    const f4 fzero = {0.f, 0.f, 0.f, 0.f};
    f4 P[4][2], Q[4][2];
#pragma unroll
    for (int i = 0; i < 4; ++i)
#pragma unroll
        for (int j = 0; j < 2; ++j) { P[i][j] = fzero; Q[i][j] = fzero; }

    float asum4[4] = {0.f, 0.f, 0.f, 0.f};

    // ---- prefetch tile 0: lane owns row 16w+l15, d-chunks 8*wl4 + 32*kk ----
    float4 va[4], vb4[4];
    {
        const float* gp = xb + (size_t)(16 * w + l15) * ND + 8 * wl4;
#pragma unroll
        for (int kk = 0; kk < 4; ++kk) {
            va[kk]  = *(const float4*)(gp + 32 * kk);
            vb4[kk] = *(const float4*)(gp + 32 * kk + 4);
        }
    }

    for (int t = 0; t < NT; ++t) {
        // ---- row L2 norm (4 lanes share a row: xor 16/32 over wl4) ----
        float ss = 0.f;
#pragma unroll
        for (int kk = 0; kk < 4; ++kk) {
            ss += va[kk].x * va[kk].x + va[kk].y * va[kk].y +
                  va[kk].z * va[kk].z + va[kk].w * va[kk].w;
            ss += vb4[kk].x * vb4[kk].x + vb4[kk].y * vb4[kk].y +
                  vb4[kk].z * vb4[kk].z + vb4[kk].w * vb4[kk].w;
        }
        ss += __shfl_xor(ss, 16);
        ss += __shfl_xor(ss, 32);
        const float sc = 1.f / fmaxf(sqrtf(ss), 1e-12f);

        // ---- fp16 hi/lo split in registers ----
        h8 xh[4], xl[4];
#pragma unroll
        for (int kk = 0; kk < 4; ++kk) {
            float f[8] = {va[kk].x * sc, va[kk].y * sc, va[kk].z * sc, va[kk].w * sc,
                          vb4[kk].x * sc, vb4[kk].y * sc, vb4[kk].z * sc, vb4[kk].w * sc};
#pragma unroll
            for (int e = 0; e < 8; ++e) {
                const _Float16 h = (_Float16)f[e];
                xh[kk][e] = h;
                xl[kk][e] = (_Float16)((f[e] - (float)h) * QSCALE);
            }
        }

        __syncthreads();   // prev tile's pooling done reading xT/aT (t=0: W ready)

        // ---- write xT (transposed copy for pooling B-frags; b16 stores) ----
        {
            const int c = 16 * w + l15;
#pragma unroll
            for (int kk = 0; kk < 4; ++kk)
#pragma unroll
                for (int e = 0; e < 8; ++e) {
                    const int d  = 32 * kk + 8 * wl4 + e;
                    const int id = xt_idx(d, c);
                    xTh[id] = xh[kk][e];
                    xTl[id] = xl[kk][e];
                }
        }

        // ---- prefetch next tile (hides under logits+softmax+pooling) ----
        if (t + 1 < NT) {
            const float* gp = xb + (size_t)((t + 1) * LT + 16 * w + l15) * ND + 8 * wl4;
#pragma unroll
            for (int kk = 0; kk < 4; ++kk) {
                va[kk]  = *(const float4*)(gp + 32 * kk);
                vb4[kk] = *(const float4*)(gp + 32 * kk + 4);
            }
        }

        // ---- logits: rows 16w..16w+15 x all 64 k, 3-term compensated MFMA ----
        f4 aP[4], aQ[4];
#pragma unroll
        for (int kt = 0; kt < 4; ++kt) { aP[kt] = fzero; aQ[kt] = fzero; }
#pragma unroll
        for (int kk = 0; kk < 4; ++kk) {
#pragma unroll
            for (int kt = 0; kt < 4; ++kt) {
                const int k    = 16 * kt + l15;
                const int base = k * 128 + ((((4 * kk + wl4) ^ (k & 15)) & 15) << 3);
                const h8 wh = *(const h8*)(Wh + base);
                const h8 wl = *(const h8*)(Wl + base);
                aP[kt] = MFMA16(xh[kk], wh, aP[kt]);
                aQ[kt] = MFMA16(xh[kk], wl, aQ[kt]);
                aQ[kt] = MFMA16(xl[kk], wh, aQ[kt]);
            }
        }

        // ---- softmax over k; buffer a in regs; accumulate asum ----
        const int crow = 16 * w + 4 * wl4;
        h4 abh[4], abl[4];   // [kt] packed over r (contiguous c in aT)
#pragma unroll
        for (int r = 0; r < 4; ++r) {
            float v0 = aP[0][r] + aQ[0][r] * QINV + bias[0];
            float v1 = aP[1][r] + aQ[1][r] * QINV + bias[1];
            float v2 = aP[2][r] + aQ[2][r] * QINV + bias[2];
            float v3 = aP[3][r] + aQ[3][r] * QINV + bias[3];
            float m = fmaxf(fmaxf(v0, v1), fmaxf(v2, v3));
            m = fmaxf(m, __shfl_xor(m, 1));
            m = fmaxf(m, __shfl_xor(m, 2));
            m = fmaxf(m, __shfl_xor(m, 4));
            m = fmaxf(m, __shfl_xor(m, 8));
            const float e0 = __expf(v0 - m);
            const float e1 = __expf(v1 - m);
            const float e2 = __expf(v2 - m);
            const float e3 = __expf(v3 - m);
            float smx = e0 + e1 + e2 + e3;
            smx += __shfl_xor(smx, 1);
            smx += __shfl_xor(smx, 2);
            smx += __shfl_xor(smx, 4);
            smx += __shfl_xor(smx, 8);
            const float inv = 1.f / smx;
            const float a0 = e0 * inv, a1 = e1 * inv, a2 = e2 * inv, a3 = e3 * inv;
            asum4[0] += a0; asum4[1] += a1; asum4[2] += a2; asum4[3] += a3;
            const _Float16 h0 = (_Float16)a0, h1 = (_Float16)a1;
            const _Float16 h2 = (_Float16)a2, h3 = (_Float16)a3;
            abh[0][r] = h0; abl[0][r] = (_Float16)((a0 - (float)h0) * QSCALE);
            abh[1][r] = h1; abl[1][r] = (_Float16)((a1 - (float)h1) * QSCALE);
            abh[2][r] = h2; abl[2][r] = (_Float16)((a2 - (float)h2) * QSCALE);
            abh[3][r] = h3; abl[3][r] = (_Float16)((a3 - (float)h3) * QSCALE);
        }
        // packed aT writes: 4 r's contiguous (same slot; crow&7 in {0,4})
#pragma unroll
        for (int kt = 0; kt < 4; ++kt) {
            const int k  = 16 * kt + l15;
            const int id = k * 64 + ((((crow >> 3) ^ (k & 7)) & 7) << 3) + (crow & 7);
            *(h4*)(aTh + id) = abh[kt];
            *(h4*)(aTl + id) = abl[kt];
        }

        __syncthreads();   // xT + aT ready

        // ---- pooling: wave owns d-band [32w,32w+32); all 64 k ----
#pragma unroll
        for (int st = 0; st < 2; ++st) {
            const int c0 = 32 * st + 8 * wl4;
            h8 ah[4], al[4];
#pragma unroll
            for (int kt = 0; kt < 4; ++kt) {
                const int k    = 16 * kt + l15;
                const int base = k * 64 + ((((c0 >> 3) ^ (k & 7)) & 7) << 3);
                ah[kt] = *(const h8*)(aTh + base);
                al[kt] = *(const h8*)(aTl + base);
            }
#pragma unroll
            for (int dt = 0; dt < 2; ++dt) {
                const int d    = 32 * w + 16 * dt + l15;
                const int base = d * 64 + ((((c0 >> 3) ^ (d & 7) ^ ((d >> 3) & 7)) & 7) << 3);
                const h8 bh = *(const h8*)(xTh + base);
                const h8 bl = *(const h8*)(xTl + base);
#pragma unroll
                for (int kt = 0; kt < 4; ++kt) {
                    P[kt][dt] = MFMA16(ah[kt], bh, P[kt][dt]);
                    Q[kt][dt] = MFMA16(ah[kt], bl, Q[kt][dt]);
                    Q[kt][dt] = MFMA16(al[kt], bh, Q[kt][dt]);
                }
            }
        }
    }

    // ---- write partial vlad (merge compensated accumulators) ----
    float* ob = wsv + (size_t)(b * NS + s) * NK * ND;
#pragma unroll
    for (int kt = 0; kt < 4; ++kt)
#pragma unroll
        for (int dt = 0; dt < 2; ++dt)
#pragma unroll
            for (int r = 0; r < 4; ++r) {
                const int k = 16 * kt + 4 * wl4 + r;
                const int d = 32 * w + 16 * dt + l15;
                ob[k * ND + d] = P[kt][dt][r] + Q[kt][dt][r] * QINV;
            }

    // ---- asum reduce: intra-wave shuffles, cross-wave via LDS (alias W) ----
#pragma unroll
    for (int kt = 0; kt < 4; ++kt) {
        float vv = asum4[kt];
        vv += __shfl_xor(vv, 16);
        vv += __shfl_xor(vv, 32);
        asum4[kt] = vv;
    }
    __syncthreads();               // everyone past last pooling; W region free
    float* scr = (float*)sm;
    if (l < 16) {
#pragma unroll
        for (int kt = 0; kt < 4; ++kt) scr[w * 64 + 16 * kt + l] = asum4[kt];
    }
    __syncthreads();
    if (tid < NK) {
        wsa[(size_t)(b * NS + s) * NK + tid] =
            scr[tid] + scr[64 + tid] + scr[128 + tid] + scr[192 + tid];
    }
}

// ---------------------------------------------------------------------------
// Kernel B: reduce NS partials, subtract asum*centroid, intra-cluster L2
// normalize, BatchNorm (inference), write output. One wave per (b,k).
// ---------------------------------------------------------------------------
__global__ __launch_bounds__(64)
void vlad_finalize_kernel(const float* __restrict__ wsv,
                          const float* __restrict__ wsa,
                          const float* __restrict__ cen,
                          const float* __restrict__ gam,
                          const float* __restrict__ bet,
                          const float* __restrict__ mu,
                          const float* __restrict__ var,
                          float* __restrict__ out)
{
    const int bk = blockIdx.x;
    const int b = bk >> 6;
    const int k = bk & 63;
    const int lane = threadIdx.x;

    const float* vb = wsv + (size_t)b * NS * NK * ND + (size_t)k * ND;
    float v0 = 0.f, v1 = 0.f, as = 0.f;
#pragma unroll
    for (int s = 0; s < NS; ++s) {
        const float* p = vb + (size_t)s * NK * ND;
        v0 += p[lane];
        v1 += p[lane + 64];
        as += wsa[(b * NS + s) * NK + k];
    }
    const int i0 = k * ND + lane;
    const int i1 = i0 + 64;
    v0 -= as * cen[i0];
    v1 -= as * cen[i1];

    float ss = v0 * v0 + v1 * v1;
#pragma unroll
    for (int o = 1; o < 64; o <<= 1) ss += __shfl_xor(ss, o);
    const float sc = 1.f / fmaxf(sqrtf(ss), 1e-12f);

    const float n0 = v0 * sc;
    const float n1 = v1 * sc;
    float* ob = out + (size_t)b * NK * ND;
    ob[i0] = gam[i0] * (n0 - mu[i0]) * rsqrtf(var[i0] + 1e-5f) + bet[i0];
    ob[i1] = gam[i1] * (n1 - mu[i1]) * rsqrtf(var[i1] + 1e-5f) + bet[i1];
}

extern "C" void kernel_launch(void* const* d_in, const int* in_sizes, int n_in,
                              void* d_out, int out_size, void* d_ws, size_t ws_size,
                              hipStream_t stream) {
    const float* x  = (const float*)d_in[0];
    const float* aw = (const float*)d_in[1];
    const float* ab = (const float*)d_in[2];
    const float* ce = (const float*)d_in[3];
    const float* g  = (const float*)d_in[4];
    const float* be = (const float*)d_in[5];
    const float* mu = (const float*)d_in[6];
    const float* va = (const float*)d_in[7];
    float* out = (float*)d_out;

    float* wsv = (float*)d_ws;                              // B*S*K*D floats (16 MiB)
    float* wsa = wsv + (size_t)NB * NS * NK * ND;           // B*S*K floats (128 KiB)

    hipLaunchKernelGGL(vlad_partial_kernel, dim3(NB * NS), dim3(256), 0, stream,
                       x, aw, ab, wsv, wsa);
    hipLaunchKernelGGL(vlad_finalize_kernel, dim3(NB * NK), dim3(64), 0, stream,
                       wsv, wsa, ce, g, be, mu, va, out);
}